// Round 1
// baseline (225.033 us; speedup 1.0000x reference)
//
#include <hip/hip_runtime.h>
#include <hip/hip_bf16.h>

#define BQ   16
#define BK2  32     // 2B
#define SEQ  256
#define HD   768
#define LDA  72     // LDS pitch (bf16 elems); mult of 8 -> 16B-aligned b128, bank stride 36%32=4 -> uniform 8-deep access

typedef __attribute__((ext_vector_type(8))) short bf16x8;
typedef __attribute__((ext_vector_type(4))) float f32x4;

__device__ inline unsigned short f2bf(float x) {
    __hip_bfloat16 h = __float2bfloat16(x);
    union { __hip_bfloat16 h; unsigned short u; } c; c.h = h;
    return c.u;
}

// ---------------- Phase 1: fp32 l2-normalize -> bf16 ----------------
// one wave per row of 768; 4 waves/block; rows = (16+32)*256 = 12288
__global__ __launch_bounds__(256) void norm_kernel(
    const float* __restrict__ q, const float* __restrict__ k,
    unsigned short* __restrict__ qn, unsigned short* __restrict__ kn)
{
    int row  = blockIdx.x * 4 + (threadIdx.x >> 6);
    int lane = threadIdx.x & 63;
    const int NQ = BQ * SEQ;
    const float* src = (row < NQ) ? q + (size_t)row * HD
                                  : k + (size_t)(row - NQ) * HD;
    unsigned short* dst = (row < NQ) ? qn + (size_t)row * HD
                                     : kn + (size_t)(row - NQ) * HD;
    float4 v[3];
    float ss = 0.f;
#pragma unroll
    for (int c = 0; c < 3; ++c) {
        v[c] = ((const float4*)src)[lane + 64 * c];
        ss += v[c].x * v[c].x + v[c].y * v[c].y + v[c].z * v[c].z + v[c].w * v[c].w;
    }
#pragma unroll
    for (int m = 1; m < 64; m <<= 1) ss += __shfl_xor(ss, m, 64);
    float inv = 1.f / fmaxf(sqrtf(ss), 1e-12f);
#pragma unroll
    for (int c = 0; c < 3; ++c) {
        ushort4 o = make_ushort4(f2bf(v[c].x * inv), f2bf(v[c].y * inv),
                                 f2bf(v[c].z * inv), f2bf(v[c].w * inv));
        ((ushort4*)dst)[lane + 64 * c] = o;
    }
}

// ---------------- Phase 2: per (i,j): sim0 = Q_i K_j^T via MFMA, fused masked
// distance-weighted softmax reduction: out[i,j] = sum_s qm[s] * (W_s / Z_s)
// with Z_s = sum_t km[t] exp(scale*sim*w[|s-t|]), W_s = sum_t km[t] exp(..)*sim.
__global__ __launch_bounds__(256) void li_kernel(
    const unsigned short* __restrict__ qn, const unsigned short* __restrict__ kn,
    const float* __restrict__ g_ls, const float* __restrict__ g_ar,
    const int* __restrict__ q_mask, const int* __restrict__ k_mask,
    float* __restrict__ out)
{
    const int j = blockIdx.x, i = blockIdx.y;
    const int tid  = threadIdx.x;
    const int wave = tid >> 6, lane = tid & 63;
    const int lg = lane >> 4, ln = lane & 15;

    __shared__ __align__(16) unsigned short As[SEQ * LDA];  // 36 KB
    __shared__ __align__(16) unsigned short Bs[64 * LDA];   // 9 KB
    __shared__ float wtab[SEQ];
    __shared__ float kmf[SEQ];
    __shared__ float red[4];

    float a0 = g_ar[0];
    float alpha = (a0 > 0.f) ? a0 : 0.01f * a0;      // leaky_relu(alpha_raw)
    float scale = __expf(g_ls[0]);

    wtab[tid] = __expf(-alpha * (float)tid);          // exp(-alpha*d), d=0..255
    kmf[tid]  = (k_mask[j * SEQ + tid] != 0) ? 1.f : 0.f;

    const unsigned short* qb = qn + (size_t)i * SEQ * HD;
    const unsigned short* kb = kn + (size_t)j * SEQ * HD;

    float Zacc[4][4] = {};   // [rm][r] per-row running exp-sum
    float Wacc[4][4] = {};   // [rm][r] per-row running exp*sim sum
    const f32x4 zero4 = {0.f, 0.f, 0.f, 0.f};

    for (int tt = 0; tt < 4; ++tt) {
        f32x4 acc[4][4];
#pragma unroll
        for (int a = 0; a < 4; ++a)
#pragma unroll
            for (int b = 0; b < 4; ++b) acc[a][b] = zero4;

        for (int kk = 0; kk < HD; kk += 64) {
            __syncthreads();   // previous stage fully consumed (also guards wtab/kmf on iter 0)
            // stage A: 256 rows x 64 cols bf16 (coalesced 16B/lane)
#pragma unroll
            for (int c = 0; c < 8; ++c) {
                int p = tid + 256 * c;          // chunk id, 8 bf16 per chunk
                int row = p >> 3, col8 = (p & 7) << 3;
                bf16x8 v = *(const bf16x8*)(qb + (size_t)row * HD + kk + col8);
                *(bf16x8*)(As + row * LDA + col8) = v;
            }
            // stage B: 64 rows (t-tile) x 64 cols
#pragma unroll
            for (int c = 0; c < 2; ++c) {
                int p = tid + 256 * c;
                int row = p >> 3, col8 = (p & 7) << 3;
                bf16x8 v = *(const bf16x8*)(kb + (size_t)(tt * 64 + row) * HD + kk + col8);
                *(bf16x8*)(Bs + row * LDA + col8) = v;
            }
            __syncthreads();
            // MFMA: wave handles rows [wave*64, +64), cols [tt*64, +64)
#pragma unroll
            for (int ks = 0; ks < 2; ++ks) {
                int kof = ks * 32 + lg * 8;     // A/B frag: [lane&15][quad*8 + 0..7]
                bf16x8 af[4], bfr[4];
#pragma unroll
                for (int rm = 0; rm < 4; ++rm)
                    af[rm] = *(const bf16x8*)(As + (wave * 64 + rm * 16 + ln) * LDA + kof);
#pragma unroll
                for (int cn = 0; cn < 4; ++cn)
                    bfr[cn] = *(const bf16x8*)(Bs + (cn * 16 + ln) * LDA + kof);
#pragma unroll
                for (int rm = 0; rm < 4; ++rm)
#pragma unroll
                    for (int cn = 0; cn < 4; ++cn)
                        acc[rm][cn] = __builtin_amdgcn_mfma_f32_16x16x32_bf16(
                            af[rm], bfr[cn], acc[rm][cn], 0, 0, 0);
            }
        }
        // epilogue for this t-tile: C/D layout col=lane&15, row=quad*4+reg
#pragma unroll
        for (int rm = 0; rm < 4; ++rm)
#pragma unroll
            for (int r = 0; r < 4; ++r) {
                int s = wave * 64 + rm * 16 + lg * 4 + r;
                float ze = 0.f, we = 0.f;
#pragma unroll
                for (int cn = 0; cn < 4; ++cn) {
                    int t = tt * 64 + cn * 16 + ln;
                    float sim = acc[rm][cn][r];
                    int d = s - t; d = (d < 0) ? -d : d;
                    float e = kmf[t] * __expf(scale * sim * wtab[d]);
                    ze += e;
                    we += e * sim;
                }
                // row lives in the 16 lanes sharing lg: butterfly over those lanes
#pragma unroll
                for (int m = 1; m < 16; m <<= 1) {
                    ze += __shfl_xor(ze, m, 64);
                    we += __shfl_xor(we, m, 64);
                }
                Zacc[rm][r] += ze;
                Wacc[rm][r] += we;
            }
    }

    // per-row per_tok = qmask * W/Z (Z==0 iff row fully masked -> 0), sum over s
    float part = 0.f;
    if (ln == 0) {
#pragma unroll
        for (int rm = 0; rm < 4; ++rm)
#pragma unroll
            for (int r = 0; r < 4; ++r) {
                int s = wave * 64 + rm * 16 + lg * 4 + r;
                float z = Zacc[rm][r];
                float pt = (z > 0.f) ? (Wacc[rm][r] / z) : 0.f;
                part += pt * (float)q_mask[i * SEQ + s];
            }
    }
#pragma unroll
    for (int m = 1; m < 64; m <<= 1) part += __shfl_xor(part, m, 64);
    if (lane == 0) red[wave] = part;
    __syncthreads();
    if (tid == 0) out[i * BK2 + j] = red[0] + red[1] + red[2] + red[3];
}

extern "C" void kernel_launch(void* const* d_in, const int* in_sizes, int n_in,
                              void* d_out, int out_size, void* d_ws, size_t ws_size,
                              hipStream_t stream) {
    const float* q  = (const float*)d_in[0];   // [16,256,768] f32
    const float* k  = (const float*)d_in[1];   // [32,256,768] f32
    const float* ls = (const float*)d_in[2];   // scalar
    const float* ar = (const float*)d_in[3];   // scalar
    const int* qm   = (const int*)d_in[4];     // [16,256]
    const int* km   = (const int*)d_in[5];     // [32,256]
    float* out      = (float*)d_out;           // [16,32] f32

    unsigned short* qn = (unsigned short*)d_ws;                 // 16*256*768 bf16
    unsigned short* kn = qn + (size_t)BQ * SEQ * HD;            // 32*256*768 bf16

    norm_kernel<<<(BQ + BK2) * SEQ / 4, 256, 0, stream>>>(q, k, qn, kn);
    li_kernel<<<dim3(BK2, BQ), 256, 0, stream>>>(qn, kn, ls, ar, qm, km, out);
}

// Round 2
// 149.669 us; speedup vs baseline: 1.5035x; 1.5035x over previous
//
#include <hip/hip_runtime.h>
#include <hip/hip_bf16.h>

#define BQ   16
#define BK2  32     // 2B
#define SEQ  256
#define HD   768

typedef __attribute__((ext_vector_type(8))) short bf16x8;
typedef __attribute__((ext_vector_type(4))) float f32x4;

__device__ __forceinline__ void glds16(const unsigned short* g, unsigned short* l) {
    __builtin_amdgcn_global_load_lds(
        (const __attribute__((address_space(1))) unsigned int*)g,
        (__attribute__((address_space(3))) unsigned int*)l, 16, 0, 0);
}

__device__ inline unsigned short f2bf(float x) {
    __hip_bfloat16 h = __float2bfloat16(x);
    union { __hip_bfloat16 h; unsigned short u; } c; c.h = h;
    return c.u;
}

// ---------------- Phase 1: fp32 l2-normalize -> bf16 ----------------
__global__ __launch_bounds__(256) void norm_kernel(
    const float* __restrict__ q, const float* __restrict__ k,
    unsigned short* __restrict__ qn, unsigned short* __restrict__ kn)
{
    int row  = blockIdx.x * 4 + (threadIdx.x >> 6);
    int lane = threadIdx.x & 63;
    const int NQ = BQ * SEQ;
    const float* src = (row < NQ) ? q + (size_t)row * HD
                                  : k + (size_t)(row - NQ) * HD;
    unsigned short* dst = (row < NQ) ? qn + (size_t)row * HD
                                     : kn + (size_t)(row - NQ) * HD;
    float4 v[3];
    float ss = 0.f;
#pragma unroll
    for (int c = 0; c < 3; ++c) {
        v[c] = ((const float4*)src)[lane + 64 * c];
        ss += v[c].x * v[c].x + v[c].y * v[c].y + v[c].z * v[c].z + v[c].w * v[c].w;
    }
#pragma unroll
    for (int m = 1; m < 64; m <<= 1) ss += __shfl_xor(ss, m, 64);
    float inv = 1.f / fmaxf(sqrtf(ss), 1e-12f);
#pragma unroll
    for (int c = 0; c < 3; ++c) {
        ushort4 o = make_ushort4(f2bf(v[c].x * inv), f2bf(v[c].y * inv),
                                 f2bf(v[c].z * inv), f2bf(v[c].w * inv));
        ((ushort4*)dst)[lane + 64 * c] = o;
    }
}

// ---------------- Phase 2: block = (i, j, sh, th) covering 128 s x 128 t.
// 4 waves as 2x2 of 64x64 MFMA tiles. glds staging, swizzled LDS (pitch 64).
// Emits partial (Z,W) per s-row per (th,wt) quadrant into ws.
__global__ __launch_bounds__(256, 3) void li_kernel(
    const unsigned short* __restrict__ qn, const unsigned short* __restrict__ kn,
    const float* __restrict__ g_ls, const float* __restrict__ g_ar,
    const int* __restrict__ k_mask, float2* __restrict__ pw)
{
    const int j  = blockIdx.x, i = blockIdx.y;
    const int sh = blockIdx.z >> 1, th = blockIdx.z & 1;
    const int tid  = threadIdx.x;
    const int w    = tid >> 6, lane = tid & 63;
    const int ln   = lane & 15, lg = lane >> 4;
    const int wsd  = w >> 1, wt = w & 1;     // wave's (s,t) quadrant

    __shared__ __align__(16) unsigned short As[128 * 64];  // 16 KB, swizzled
    __shared__ __align__(16) unsigned short Bs[128 * 64];  // 16 KB, swizzled
    __shared__ float w2[SEQ];     // scale * exp(-alpha*d)
    __shared__ float kmB[128];

    float a0 = g_ar[0];
    float alpha = (a0 > 0.f) ? a0 : 0.01f * a0;        // leaky_relu
    float scale = __expf(g_ls[0]);
    w2[tid] = scale * __expf(-alpha * (float)tid);
    if (tid < 128) kmB[tid] = (k_mask[j * SEQ + th * 128 + tid] != 0) ? 1.f : 0.f;

    // glds staging: lane covers row (base + lane>>3), swizzled source chunk
    const int rl  = lane >> 3;
    const int gch = (lane & 7) ^ rl;      // LDS slot (lane&7) holds global chunk slot^row&7
    const unsigned short* aq = qn + ((size_t)i * SEQ + sh * 128 + w * 8 + rl) * HD + gch * 8;
    const unsigned short* bq = kn + ((size_t)j * SEQ + th * 128 + w * 8 + rl) * HD + gch * 8;
    unsigned short* al = As + (w * 8) * 64;
    unsigned short* bl = Bs + (w * 8) * 64;

    f32x4 acc[4][4];
    const f32x4 zero4 = {0.f, 0.f, 0.f, 0.f};
#pragma unroll
    for (int a = 0; a < 4; ++a)
#pragma unroll
        for (int b = 0; b < 4; ++b) acc[a][b] = zero4;

    for (int kk = 0; kk < HD; kk += 64) {
        __syncthreads();                       // prev stage consumed
#pragma unroll
        for (int c = 0; c < 4; ++c) {
            glds16(aq + kk + c * (32 * HD), al + c * (32 * 64));
            glds16(bq + kk + c * (32 * HD), bl + c * (32 * 64));
        }
        __syncthreads();                       // compiler drains vmcnt before barrier
        const bf16x8* A8 = (const bf16x8*)As;
        const bf16x8* B8 = (const bf16x8*)Bs;
#pragma unroll
        for (int ks = 0; ks < 2; ++ks) {
            const int ch = (ks * 4 + lg) ^ (ln & 7);   // unswizzle
            bf16x8 af[4], bfr[4];
#pragma unroll
            for (int rm = 0; rm < 4; ++rm)
                af[rm] = A8[(wsd * 64 + rm * 16 + ln) * 8 + ch];
#pragma unroll
            for (int cn = 0; cn < 4; ++cn)
                bfr[cn] = B8[(wt * 64 + cn * 16 + ln) * 8 + ch];
#pragma unroll
            for (int rm = 0; rm < 4; ++rm)
#pragma unroll
                for (int cn = 0; cn < 4; ++cn)
                    acc[rm][cn] = __builtin_amdgcn_mfma_f32_16x16x32_bf16(
                        af[rm], bfr[cn], acc[rm][cn], 0, 0, 0);
        }
    }

    // epilogue (once): C/D layout col=ln (t), row=lg*4+r (s)
    float kmv[4];
#pragma unroll
    for (int cn = 0; cn < 4; ++cn) kmv[cn] = kmB[wt * 64 + cn * 16 + ln];
    const int tg = th * 128 + wt * 64 + ln;

#pragma unroll
    for (int rm = 0; rm < 4; ++rm)
#pragma unroll
        for (int r = 0; r < 4; ++r) {
            int sl = wsd * 64 + rm * 16 + lg * 4 + r;   // s within block's 128
            int s  = sh * 128 + sl;
            float ze = 0.f, we = 0.f;
#pragma unroll
            for (int cn = 0; cn < 4; ++cn) {
                int t = tg + cn * 16;
                float sim = acc[rm][cn][r];
                int d = s - t; d = (d < 0) ? -d : d;
                float e = kmv[cn] * __expf(sim * w2[d]);
                ze += e;
                we = fmaf(e, sim, we);
            }
#pragma unroll
            for (int m = 1; m < 16; m <<= 1) {          // reduce over t-16 lanes
                ze += __shfl_xor(ze, m, 64);
                we += __shfl_xor(we, m, 64);
            }
            if (ln == 0) {
                size_t idx = ((size_t)((i * BK2 + j) * SEQ) + s) * 4 + th * 2 + wt;
                pw[idx] = make_float2(ze, we);
            }
        }
}

// ---------------- Phase 3: combine partials, divide, mask, reduce over s ----
__global__ __launch_bounds__(256) void reduce_kernel(
    const float2* __restrict__ pw, const int* __restrict__ q_mask,
    float* __restrict__ out)
{
    int j = blockIdx.x, i = blockIdx.y, s = threadIdx.x;
    const float4* p = (const float4*)(pw + ((size_t)(i * BK2 + j) * SEQ + s) * 4);
    float4 a = p[0], b = p[1];                 // (Z0,W0,Z1,W1),(Z2,W2,Z3,W3)
    float Z = a.x + a.z + b.x + b.z;
    float W = a.y + a.w + b.y + b.w;
    float pt = (Z > 0.f) ? (W / Z) : 0.f;
    pt *= (float)q_mask[i * SEQ + s];
#pragma unroll
    for (int m = 1; m < 64; m <<= 1) pt += __shfl_xor(pt, m, 64);
    __shared__ float rb[4];
    int wv = s >> 6, lane = s & 63;
    if (lane == 0) rb[wv] = pt;
    __syncthreads();
    if (s == 0) out[i * BK2 + j] = rb[0] + rb[1] + rb[2] + rb[3];
}

extern "C" void kernel_launch(void* const* d_in, const int* in_sizes, int n_in,
                              void* d_out, int out_size, void* d_ws, size_t ws_size,
                              hipStream_t stream) {
    const float* q  = (const float*)d_in[0];   // [16,256,768] f32
    const float* k  = (const float*)d_in[1];   // [32,256,768] f32
    const float* ls = (const float*)d_in[2];   // scalar
    const float* ar = (const float*)d_in[3];   // scalar
    const int* qm   = (const int*)d_in[4];     // [16,256]
    const int* km   = (const int*)d_in[5];     // [32,256]
    float* out      = (float*)d_out;           // [16,32] f32

    unsigned short* qn = (unsigned short*)d_ws;            // 16*256*768 bf16
    unsigned short* kn = qn + (size_t)BQ * SEQ * HD;       // 32*256*768 bf16
    float2* pw = (float2*)((char*)d_ws + (size_t)(BQ + BK2) * SEQ * HD * 2); // 4 MB partials

    norm_kernel<<<(BQ + BK2) * SEQ / 4, 256, 0, stream>>>(q, k, qn, kn);
    li_kernel<<<dim3(BK2, BQ, 4), 256, 0, stream>>>(qn, kn, ls, ar, km, pw);
    reduce_kernel<<<dim3(BK2, BQ), 256, 0, stream>>>(pw, qm, out);
}

// Round 3
// 141.054 us; speedup vs baseline: 1.5954x; 1.0611x over previous
//
#include <hip/hip_runtime.h>
#include <hip/hip_bf16.h>

#define BQ   16
#define BK2  32     // 2B
#define SEQ  256
#define HD   768

typedef __attribute__((ext_vector_type(8))) short bf16x8;
typedef __attribute__((ext_vector_type(4))) float f32x4;

__device__ __forceinline__ void glds16(const unsigned short* g, unsigned short* l) {
    __builtin_amdgcn_global_load_lds(
        (const __attribute__((address_space(1))) unsigned int*)g,
        (__attribute__((address_space(3))) unsigned int*)l, 16, 0, 0);
}

// branch-free RNE fp32->bf16, packed two at a time
__device__ __forceinline__ unsigned int pack2_bf16(float a, float b) {
    unsigned ua = __float_as_uint(a), ub = __float_as_uint(b);
    ua += 0x7FFFu + ((ua >> 16) & 1u);
    ub += 0x7FFFu + ((ub >> 16) & 1u);
    return (ua >> 16) | (ub & 0xFFFF0000u);
}

// ---------------- Phase 1: fp32 l2-normalize -> bf16 (+ zero d_out) --------
__global__ __launch_bounds__(256) void norm_kernel(
    const float* __restrict__ q, const float* __restrict__ k,
    unsigned short* __restrict__ qn, unsigned short* __restrict__ kn,
    float* __restrict__ out)
{
    if (blockIdx.x == 0 && threadIdx.x < 256) {      // zero 512-elem out for li's atomics
        out[threadIdx.x] = 0.f; out[threadIdx.x + 256] = 0.f;
    }
    int row  = blockIdx.x * 4 + (threadIdx.x >> 6);
    int lane = threadIdx.x & 63;
    const int NQ = BQ * SEQ;
    const float* src = (row < NQ) ? q + (size_t)row * HD
                                  : k + (size_t)(row - NQ) * HD;
    unsigned int* dst = (unsigned int*)((row < NQ) ? qn + (size_t)row * HD
                                                   : kn + (size_t)(row - NQ) * HD);
    float4 v[3];
    float ss = 0.f;
#pragma unroll
    for (int c = 0; c < 3; ++c) {
        v[c] = ((const float4*)src)[lane + 64 * c];
        ss += v[c].x * v[c].x + v[c].y * v[c].y + v[c].z * v[c].z + v[c].w * v[c].w;
    }
#pragma unroll
    for (int m = 1; m < 64; m <<= 1) ss += __shfl_xor(ss, m, 64);
    float inv = rsqrtf(fmaxf(ss, 1e-24f));
#pragma unroll
    for (int c = 0; c < 3; ++c) {
        uint2 o = make_uint2(pack2_bf16(v[c].x * inv, v[c].y * inv),
                             pack2_bf16(v[c].z * inv, v[c].w * inv));
        ((uint2*)dst)[lane + 64 * c] = o;
    }
}

// ---------------- Phase 2: block = (j, i, sh) covering 128 s x 256 t (full t)
// 8 waves as 2(s) x 4(t) of 64x64 MFMA tiles. glds staging, swizzled LDS.
// Full softmax per row completes in-block; one atomicAdd per block.
__global__ __launch_bounds__(512, 2) void li_kernel(
    const unsigned short* __restrict__ qn, const unsigned short* __restrict__ kn,
    const float* __restrict__ g_ls, const float* __restrict__ g_ar,
    const int* __restrict__ q_mask, const int* __restrict__ k_mask,
    float* __restrict__ out)
{
    const int j  = blockIdx.x, i = blockIdx.y, sh = blockIdx.z;
    const int tid  = threadIdx.x;
    const int w    = tid >> 6, lane = tid & 63;
    const int ln   = lane & 15, lg = lane >> 4;
    const int wsd  = w >> 2, wt = w & 3;     // wave = (s-half, t-quarter)

    __shared__ __align__(16) unsigned short As[128 * 64];  // 16 KB, swizzled
    __shared__ __align__(16) unsigned short Bs[256 * 64];  // 32 KB, swizzled
    __shared__ float w2[SEQ];      // scale * exp(-alpha*d)
    __shared__ float kmB[SEQ];
    __shared__ float red[8];

    float a0 = g_ar[0];
    float alpha = (a0 > 0.f) ? a0 : 0.01f * a0;        // leaky_relu
    float scale = __expf(g_ls[0]);
    if (tid < 256) w2[tid] = scale * __expf(-alpha * (float)tid);
    else           kmB[tid - 256] = (k_mask[j * SEQ + (tid - 256)] != 0) ? 1.f : 0.f;

    // glds staging: lane covers row (base + lane>>3), swizzled source chunk
    const int rl  = lane >> 3;
    const int gch = (lane & 7) ^ rl;      // LDS chunk slot (lane&7) <- global chunk (lane&7)^row&7
    const unsigned short* aq = qn + ((size_t)i * SEQ + sh * 128 + w * 8 + rl) * HD + gch * 8;
    const unsigned short* bq = kn + ((size_t)j * SEQ + w * 8 + rl) * HD + gch * 8;
    unsigned short* al = As + (w * 8) * 64;
    unsigned short* bl = Bs + (w * 8) * 64;

    f32x4 acc[4][4];
    const f32x4 zero4 = {0.f, 0.f, 0.f, 0.f};
#pragma unroll
    for (int a = 0; a < 4; ++a)
#pragma unroll
        for (int b = 0; b < 4; ++b) acc[a][b] = zero4;

    for (int kk = 0; kk < HD; kk += 64) {
        __syncthreads();                       // prev stage consumed
        glds16(aq + kk,           al);                 // A rows 0..63 (w*8+rl)
        glds16(aq + kk + 64 * HD, al + 64 * 64);       // A rows 64..127
#pragma unroll
        for (int c = 0; c < 4; ++c)                    // B rows 0..255
            glds16(bq + kk + c * (64 * HD), bl + c * (64 * 64));
        __syncthreads();                       // vmcnt drained before barrier
        const bf16x8* A8 = (const bf16x8*)As;
        const bf16x8* B8 = (const bf16x8*)Bs;
#pragma unroll
        for (int ks = 0; ks < 2; ++ks) {
            const int ch = (ks * 4 + lg) ^ (ln & 7);   // unswizzle
            bf16x8 af[4], bfr[4];
#pragma unroll
            for (int rm = 0; rm < 4; ++rm)
                af[rm] = A8[(wsd * 64 + rm * 16 + ln) * 8 + ch];
#pragma unroll
            for (int cn = 0; cn < 4; ++cn)
                bfr[cn] = B8[(wt * 64 + cn * 16 + ln) * 8 + ch];
#pragma unroll
            for (int rm = 0; rm < 4; ++rm)
#pragma unroll
                for (int cn = 0; cn < 4; ++cn)
                    acc[rm][cn] = __builtin_amdgcn_mfma_f32_16x16x32_bf16(
                        af[rm], bfr[cn], acc[rm][cn], 0, 0, 0);
        }
    }

    // epilogue: C/D layout col=ln (t), row=lg*4+r (s)
    __syncthreads();                    // all As/Bs reads done; reuse As as scratch
    float* zs  = (float*)As;            // [128][4] Z partials per (srow, wt)
    float* wsc = zs + 512;              // [128][4] W partials

#pragma unroll
    for (int rm = 0; rm < 4; ++rm)
#pragma unroll
        for (int r = 0; r < 4; ++r) {
            int srow = wsd * 64 + rm * 16 + lg * 4 + r;   // s within block's 128
            int s  = sh * 128 + srow;
            float ze = 0.f, we = 0.f;
#pragma unroll
            for (int cn = 0; cn < 4; ++cn) {
                int t = wt * 64 + cn * 16 + ln;           // global t (full 256 in-block)
                float sim = acc[rm][cn][r];
                int d = s - t; d = (d < 0) ? -d : d;
                float e = kmB[t] * __expf(sim * w2[d]);
                ze += e;
                we = fmaf(e, sim, we);
            }
#pragma unroll
            for (int m = 1; m < 16; m <<= 1) {            // reduce over t-16 lanes
                ze += __shfl_xor(ze, m, 64);
                we += __shfl_xor(we, m, 64);
            }
            if (ln == 0) { zs[srow * 4 + wt] = ze; wsc[srow * 4 + wt] = we; }
        }
    __syncthreads();

    float part = 0.f;
    if (tid < 128) {
        const float4 Z4 = ((const float4*)zs)[tid];
        const float4 W4 = ((const float4*)wsc)[tid];
        float Z = Z4.x + Z4.y + Z4.z + Z4.w;
        float W = W4.x + W4.y + W4.z + W4.w;
        float pt = (Z > 0.f) ? (W / Z) : 0.f;
        part = pt * (float)q_mask[i * SEQ + sh * 128 + tid];
    }
#pragma unroll
    for (int m = 1; m < 64; m <<= 1) part += __shfl_xor(part, m, 64);
    if (lane == 0) red[w] = part;
    __syncthreads();
    if (tid == 0) {
        float tot = red[0] + red[1] + red[2] + red[3]
                  + red[4] + red[5] + red[6] + red[7];
        atomicAdd(&out[i * BK2 + j], tot);
    }
}

extern "C" void kernel_launch(void* const* d_in, const int* in_sizes, int n_in,
                              void* d_out, int out_size, void* d_ws, size_t ws_size,
                              hipStream_t stream) {
    const float* q  = (const float*)d_in[0];   // [16,256,768] f32
    const float* k  = (const float*)d_in[1];   // [32,256,768] f32
    const float* ls = (const float*)d_in[2];   // scalar
    const float* ar = (const float*)d_in[3];   // scalar
    const int* qm   = (const int*)d_in[4];     // [16,256]
    const int* km   = (const int*)d_in[5];     // [32,256]
    float* out      = (float*)d_out;           // [16,32] f32

    unsigned short* qn = (unsigned short*)d_ws;            // 16*256*768 bf16
    unsigned short* kn = qn + (size_t)BQ * SEQ * HD;       // 32*256*768 bf16

    norm_kernel<<<(BQ + BK2) * SEQ / 4, 256, 0, stream>>>(q, k, qn, kn, (float*)d_out);
    li_kernel<<<dim3(BK2, BQ, 2), 512, 0, stream>>>(qn, kn, ls, ar, qm, km, (float*)d_out);
}